// Round 1
// baseline (216.328 us; speedup 1.0000x reference)
//
#include <hip/hip_runtime.h>

#define BB 8
#define NN 2048
#define EE 64
#define DD 128
#define BN (BB * NN)
#define TI 64
#define TJ 32

// ---------- pre-kernel: sq[b*N+i] = ||emb[b,i,:]||^2 (one wave per row) ----------
__global__ __launch_bounds__(256) void sq_kernel(const float* __restrict__ emb,
                                                 float* __restrict__ sq) {
    int t = threadIdx.x;
    int lane = t & 63;
    int row = blockIdx.x * 4 + (t >> 6);
    float v = emb[(size_t)row * EE + lane];
    float p = v * v;
#pragma unroll
    for (int off = 32; off > 0; off >>= 1) p += __shfl_xor(p, off);
    if (lane == 0) sq[row] = p;
}

__device__ __forceinline__ void dot4(float& acc, const float4 a, const float4 b) {
    acc = fmaf(a.x, b.x, acc);
    acc = fmaf(a.y, b.y, acc);
    acc = fmaf(a.z, b.z, acc);
    acc = fmaf(a.w, b.w, acc);
}

// ---------- main kernel: flash-style streaming attention, fp32 vector ----------
// grid = (N/TI, B, njs). Each block: 64 i-rows, j-range split njs ways.
// If njs == 1 writes normalized output directly; else writes partial num/den to ws.
__global__ __launch_bounds__(256) void attn_kernel(const float* __restrict__ emb,
                                                   const float* __restrict__ z,
                                                   const float* __restrict__ sq,
                                                   float* __restrict__ outnum,
                                                   float* __restrict__ den,
                                                   int njs) {
    // LDS: emb tiles stored as float4 granules, granule g of row r at (g ^ (r&15))
    // -> conflict-free b128 reads in phase 1. ST (scores, transposed) padded to 65.
    __shared__ float4 embI[TI * 16];
    __shared__ float4 embJ[TJ * 16];
    __shared__ float4 zL[TJ * 32];
    __shared__ float ST[TJ * 65];
    __shared__ float sqJ[TJ];

    const int t = threadIdx.x;
    const int ib = blockIdx.x * TI;
    const int b = blockIdx.y;
    const int js = blockIdx.z;

    const float* embB = emb + (size_t)b * NN * EE;
    const float* zB = z + (size_t)b * NN * DD;
    const float* sqB = sq + (size_t)b * NN;

    // stage embI tile once (swizzled)
#pragma unroll
    for (int k = 0; k < 4; ++k) {
        int idx = t + k * 256;
        int r = idx >> 4, g = idx & 15;
        float4 v = reinterpret_cast<const float4*>(embB + (size_t)(ib + r) * EE)[g];
        embI[r * 16 + (g ^ (r & 15))] = v;
    }

    const int i0 = (t >> 4) * 4;  // this thread's 4 i-rows (same in both phases)
    const int s = t & 15;

    float sqIr[4];
#pragma unroll
    for (int ii = 0; ii < 4; ++ii) sqIr[ii] = sqB[ib + i0 + ii];

    float4 acc[4][2];
#pragma unroll
    for (int ii = 0; ii < 4; ++ii) {
        acc[ii][0] = make_float4(0.f, 0.f, 0.f, 0.f);
        acc[ii][1] = make_float4(0.f, 0.f, 0.f, 0.f);
    }
    float dsum[4] = {0.f, 0.f, 0.f, 0.f};

    const int ntiles = (NN / TJ) / njs;
    const int jt0 = js * ntiles;

    for (int jt = jt0; jt < jt0 + ntiles; ++jt) {
        const int jb = jt * TJ;
        __syncthreads();  // previous iteration done with embJ/zL/ST
        // stage embJ (swizzled) + z tile + sqJ
#pragma unroll
        for (int k = 0; k < 2; ++k) {
            int idx = t + k * 256;
            int r = idx >> 4, g = idx & 15;
            float4 v = reinterpret_cast<const float4*>(embB + (size_t)(jb + r) * EE)[g];
            embJ[r * 16 + (g ^ (r & 15))] = v;
        }
#pragma unroll
        for (int k = 0; k < 4; ++k) {
            int idx = t + k * 256;
            int r = idx >> 5, c = idx & 31;
            zL[r * 32 + c] = reinterpret_cast<const float4*>(zB + (size_t)(jb + r) * DD)[c];
        }
        if (t < TJ) sqJ[t] = sqB[jb + t];
        __syncthreads();

        // ---- phase 1: S = exp(-max(sqI + sqJ - 2*inner, 0)) -> ST (transposed) ----
        float inn[4][2] = {{0.f, 0.f}, {0.f, 0.f}, {0.f, 0.f}, {0.f, 0.f}};
#pragma unroll
        for (int g = 0; g < 16; ++g) {
            float4 b0 = embJ[s * 16 + (g ^ s)];
            float4 b1 = embJ[(s + 16) * 16 + (g ^ s)];  // (s+16)&15 == s
            float4 a0 = embI[(i0 + 0) * 16 + (g ^ ((i0 + 0) & 15))];
            float4 a1 = embI[(i0 + 1) * 16 + (g ^ ((i0 + 1) & 15))];
            float4 a2 = embI[(i0 + 2) * 16 + (g ^ ((i0 + 2) & 15))];
            float4 a3 = embI[(i0 + 3) * 16 + (g ^ ((i0 + 3) & 15))];
            dot4(inn[0][0], a0, b0); dot4(inn[0][1], a0, b1);
            dot4(inn[1][0], a1, b0); dot4(inn[1][1], a1, b1);
            dot4(inn[2][0], a2, b0); dot4(inn[2][1], a2, b1);
            dot4(inn[3][0], a3, b0); dot4(inn[3][1], a3, b1);
        }
#pragma unroll
        for (int ii = 0; ii < 4; ++ii) {
#pragma unroll
            for (int jj = 0; jj < 2; ++jj) {
                int j = s + 16 * jj;
                float d2 = fmaxf(sqIr[ii] + sqJ[j] - 2.f * inn[ii][jj], 0.f);
                float w = __expf(-d2);
                dsum[ii] += w;
                ST[j * 65 + i0 + ii] = w;
            }
        }
        __syncthreads();

        // ---- phase 2: acc[i,d] += w[i,j] * z[j,d] ----
#pragma unroll 4
        for (int j = 0; j < TJ; ++j) {
            float4 za = zL[j * 32 + 2 * s];
            float4 zb = zL[j * 32 + 2 * s + 1];
#pragma unroll
            for (int ii = 0; ii < 4; ++ii) {
                float w = ST[j * 65 + i0 + ii];
                acc[ii][0].x = fmaf(w, za.x, acc[ii][0].x);
                acc[ii][0].y = fmaf(w, za.y, acc[ii][0].y);
                acc[ii][0].z = fmaf(w, za.z, acc[ii][0].z);
                acc[ii][0].w = fmaf(w, za.w, acc[ii][0].w);
                acc[ii][1].x = fmaf(w, zb.x, acc[ii][1].x);
                acc[ii][1].y = fmaf(w, zb.y, acc[ii][1].y);
                acc[ii][1].z = fmaf(w, zb.z, acc[ii][1].z);
                acc[ii][1].w = fmaf(w, zb.w, acc[ii][1].w);
            }
        }
    }

    // dsum currently holds this thread's j-subset; reduce across the 16 lanes
    // (s-group) that share the same 4 i-rows.
#pragma unroll
    for (int off = 1; off < 16; off <<= 1) {
#pragma unroll
        for (int ii = 0; ii < 4; ++ii) dsum[ii] += __shfl_xor(dsum[ii], off);
    }

    const int d0 = s * 8;
    if (njs == 1) {
#pragma unroll
        for (int ii = 0; ii < 4; ++ii) {
            float inv = 1.0f / dsum[ii];  // diagonal term guarantees dsum >= 1
            float4 o0 = make_float4(acc[ii][0].x * inv, acc[ii][0].y * inv,
                                    acc[ii][0].z * inv, acc[ii][0].w * inv);
            float4 o1 = make_float4(acc[ii][1].x * inv, acc[ii][1].y * inv,
                                    acc[ii][1].z * inv, acc[ii][1].w * inv);
            float4* op = reinterpret_cast<float4*>(outnum + ((size_t)(b * NN + ib + i0 + ii)) * DD + d0);
            op[0] = o0;
            op[1] = o1;
        }
    } else {
#pragma unroll
        for (int ii = 0; ii < 4; ++ii) {
            size_t row = (size_t)js * BN + (size_t)b * NN + ib + i0 + ii;
            float4* np_ = reinterpret_cast<float4*>(outnum + row * DD + d0);
            np_[0] = acc[ii][0];
            np_[1] = acc[ii][1];
            if (s == 0) den[row] = dsum[ii];
        }
    }
}

// ---------- reduce kernel (njs > 1): out = sum_js num / sum_js den ----------
__global__ __launch_bounds__(256) void reduce_kernel(const float4* __restrict__ num,
                                                     const float* __restrict__ den,
                                                     float4* __restrict__ out,
                                                     int njs) {
    int i4 = blockIdx.x * 256 + threadIdx.x;  // float4 index into [B*N, D]
    int row = i4 >> 5;                        // D/4 = 32 float4 per row
    float4 ns = make_float4(0.f, 0.f, 0.f, 0.f);
    float ds = 0.f;
    for (int js = 0; js < njs; ++js) {
        float4 v = num[(size_t)js * ((size_t)BN * (DD / 4)) + i4];
        ns.x += v.x; ns.y += v.y; ns.z += v.z; ns.w += v.w;
        ds += den[(size_t)js * BN + row];
    }
    float inv = 1.0f / ds;
    out[i4] = make_float4(ns.x * inv, ns.y * inv, ns.z * inv, ns.w * inv);
}

extern "C" void kernel_launch(void* const* d_in, const int* in_sizes, int n_in,
                              void* d_out, int out_size, void* d_ws, size_t ws_size,
                              hipStream_t stream) {
    (void)in_sizes; (void)n_in; (void)out_size;
    const float* emb = (const float*)d_in[0];
    const float* z = (const float*)d_in[1];
    float* out = (float*)d_out;
    float* ws = (float*)d_ws;

    // ws layout: sq[BN] | den[njs*BN] | num[njs*BN*D]
    int njs = 1;
    if (ws_size >= 4ull * ((size_t)BN + 4ull * BN * (DD + 1))) njs = 4;
    else if (ws_size >= 4ull * ((size_t)BN + 2ull * BN * (DD + 1))) njs = 2;

    float* sqw = ws;
    float* denw = ws + BN;
    float* numw = denw + (size_t)njs * BN;

    sq_kernel<<<BN / 4, 256, 0, stream>>>(emb, sqw);

    dim3 grid(NN / TI, BB, njs);
    attn_kernel<<<grid, 256, 0, stream>>>(emb, z, sqw, njs == 1 ? out : numw, denw, njs);

    if (njs > 1) {
        reduce_kernel<<<(BN * (DD / 4)) / 256, 256, 0, stream>>>(
            (const float4*)numw, denw, (float4*)out, njs);
    }
}

// Round 4
// 56.500 us; speedup vs baseline: 3.8288x; 3.8288x over previous
//
#include <hip/hip_runtime.h>
#include <hip/hip_bf16.h>

#define BB 8
#define NN 2048
#define EE 64
#define DD 128
#define BN (BB * NN)

typedef __attribute__((ext_vector_type(8))) short short8v;
typedef __attribute__((ext_vector_type(4))) float float4v;

__device__ __forceinline__ short f2bf(float f) {
    __hip_bfloat16 h = __float2bfloat16(f);
    return *reinterpret_cast<short*>(&h);
}
__device__ __forceinline__ uint32_t pack2bf(float a, float b) {
    return (uint32_t)(uint16_t)f2bf(a) | ((uint32_t)(uint16_t)f2bf(b) << 16);
}

// ---------- sq[b*N+i] = ||bf16(emb[b,i,:])||^2 (bf16-rounded so diag d2 ~= 0) ----------
__global__ __launch_bounds__(256) void sq_kernel(const float* __restrict__ emb,
                                                 float* __restrict__ sq) {
    int t = threadIdx.x;
    int lane = t & 63;
    int row = blockIdx.x * 4 + (t >> 6);
    float v = __bfloat162float(__float2bfloat16(emb[(size_t)row * EE + lane]));
    float p = v * v;
#pragma unroll
    for (int off = 32; off > 0; off >>= 1) p += __shfl_xor(p, off);
    if (lane == 0) sq[row] = p;
}

// ---------- embq: fragment-ordered bf16 emb ----------
// slot flat idx = ((b*128 + r16)*2 + ke)*64 + s ; holds emb[b][r16*16 + (s&15)][ke*32 + ((s>>4)&3)*8 + e]
__global__ __launch_bounds__(256) void embq_kernel(const float* __restrict__ emb,
                                                   short* __restrict__ embq) {
    int gid = blockIdx.x * 256 + threadIdx.x;  // 131072 total
    int s = gid & 63;
    int ke = (gid >> 6) & 1;
    int r16 = (gid >> 7) & 127;
    int b = gid >> 14;
    int i = r16 * 16 + (s & 15);
    int e0 = ke * 32 + ((s >> 4) & 3) * 8;
    const float* src = emb + ((size_t)(b * NN + i)) * EE + e0;
    short8v o;
#pragma unroll
    for (int e = 0; e < 8; ++e) o[e] = f2bf(src[e]);
    *reinterpret_cast<short8v*>(embq + (size_t)gid * 8) = o;
}

// ---------- zq: fragment-ordered bf16 z (B-operand for PV) ----------
// slot flat idx = ((b*64 + jkt)*8 + nt)*64 + s ; holds z[b][jkt*32 + ((s>>4)&3)*8 + e][nt*16 + (s&15)]
__global__ __launch_bounds__(256) void zq_kernel(const float* __restrict__ z,
                                                 short* __restrict__ zq) {
    __shared__ float zl[64 * 129];
    int bid = blockIdx.x;  // b*32 + jt
    int b = bid >> 5;
    int jt = bid & 31;
    int jb = jt * 64;
    int t = threadIdx.x;
#pragma unroll
    for (int k = 0; k < 8; ++k) {
        int idx = t + k * 256;  // float4 units over [64][128]
        int jl = idx >> 5, c4 = idx & 31;
        float4 v = reinterpret_cast<const float4*>(z + ((size_t)(b * NN + jb + jl)) * DD)[c4];
        float* p = &zl[jl * 129 + c4 * 4];
        p[0] = v.x; p[1] = v.y; p[2] = v.z; p[3] = v.w;
    }
    __syncthreads();
#pragma unroll
    for (int k = 0; k < 4; ++k) {
        int sid = t + k * 256;  // 0..1023 slots
        int blk = sid >> 6, s = sid & 63;
        int ktl = blk >> 3, nt = blk & 7;
        int d = nt * 16 + (s & 15);
        int jl = ktl * 32 + ((s >> 4) & 3) * 8;
        short8v o;
#pragma unroll
        for (int e = 0; e < 8; ++e) o[e] = f2bf(zl[(jl + e) * 129 + d]);
        *reinterpret_cast<short8v*>(zq + ((size_t)((b * 64 + jt * 2 + ktl) * 8 + nt) * 64 + s) * 8) = o;
    }
}

// ---------- main MFMA attention (swapped QK^T + in-wave shfl redistribution) ----------
// grid: bid = (js*32 + it)*8 + b. 256 threads = 4 waves.
// QK: wave w owns rows [w*16, w*16+16). Swapped mfma(embJ, embI) -> lane (g,c) holds
//     S[i = w*16 + c][j = J*16 + 4g + r] : row-local P.
// PV: wave w owns (i32 = w>>1, d64 = w&1).
__global__ __launch_bounds__(256, 2) void attn_mfma(const short* __restrict__ embq,
                                                    const short* __restrict__ zq,
                                                    const float* __restrict__ sq,
                                                    float* __restrict__ outnum,
                                                    float* __restrict__ den,
                                                    int njs) {
    __shared__ int4 sEmbI[512];  // [ifr(4)][ke(2)][64 lanes] 16B slots
    __shared__ int4 sEmbJ[512];  // [jfr(4)][ke(2)][64]
    __shared__ int4 sZ[1024];    // [kt(2)][nt(8)][64]
    __shared__ int4 sPA[512];    // [wave(4)][kt(2)][64] PV A-fragments, lane-linear
    __shared__ float sSqJ[64];
    __shared__ float sDen[64];

    const int t = threadIdx.x;
    const int bid = blockIdx.x;
    const int b = bid & 7;
    const int q = bid >> 3;
    const int it = q & 31;
    const int js = q >> 5;
    const int ib = it * 64;
    const int w = t >> 6;
    const int l = t & 63;
    const int g = (l >> 4) & 3;
    const int c = l & 15;

    const int4* embqI4 = (const int4*)embq;
    const int4* zqI4 = (const int4*)zq;
    const float* sqB = sq + b * NN;

    // stage embI fragment region (rows ib..ib+63): 512 contiguous 16B slots
    {
        const int4* src = embqI4 + (size_t)(b * 128 + (ib >> 4)) * 2 * 64;
        sEmbI[t] = src[t];
        sEmbI[t + 256] = src[t + 256];
    }
    __syncthreads();

    short8v qkB[2];  // this wave's embI fragments (B operand of swapped QK)
    qkB[0] = *reinterpret_cast<const short8v*>(&sEmbI[(w * 2 + 0) * 64 + l]);
    qkB[1] = *reinterpret_cast<const short8v*>(&sEmbI[(w * 2 + 1) * 64 + l]);

    const float sqi = sqB[ib + w * 16 + c];  // this lane's own row norm

    float dsum = 0.f;
    float4v accPV[2][4];
#pragma unroll
    for (int ifr = 0; ifr < 2; ++ifr)
#pragma unroll
        for (int nt = 0; nt < 4; ++nt) accPV[ifr][nt] = (float4v){0.f, 0.f, 0.f, 0.f};

    const int h = w >> 1, dh = w & 1;
    const int srcbase = ((l >> 4) & 1) * 32 + (l & 15);  // shfl source: 32*(g&1) + 16u + c

    const int ntiles = 32 / njs;
    const int jt0 = js * ntiles;

    for (int jt = jt0; jt < jt0 + ntiles; ++jt) {
        __syncthreads();  // (a) previous tile fully consumed
        {
            const int jb = jt * 64;
            const int4* srcJ = embqI4 + (size_t)(b * 128 + (jb >> 4)) * 2 * 64;
            sEmbJ[t] = srcJ[t];
            sEmbJ[t + 256] = srcJ[t + 256];
            const int4* srcZ = zqI4 + (size_t)((b * 64 + jt * 2) * 8) * 64;
#pragma unroll
            for (int k = 0; k < 4; ++k) sZ[t + k * 256] = srcZ[t + k * 256];
            if (t < 64) sSqJ[t] = sqB[jb + t];
        }
        __syncthreads();  // (b) staging visible

        // ---- QK (swapped): for each 16-j block J, D = mfma(embJ(J), embI(w)) = S^T tile.
        // Lane (g,c) reg r: S[i = w*16 + c][j = J*16 + 4g + r].
        float pw[4][4];       // [J][r]
        uint32_t pk[4][2];    // [J][pair]
#pragma unroll
        for (int J = 0; J < 4; ++J) {
            float4v sfr = (float4v){0.f, 0.f, 0.f, 0.f};
#pragma unroll
            for (int ke = 0; ke < 2; ++ke) {
                short8v afrag = *reinterpret_cast<const short8v*>(&sEmbJ[(J * 2 + ke) * 64 + l]);
                sfr = __builtin_amdgcn_mfma_f32_16x16x32_bf16(afrag, qkB[ke], sfr, 0, 0, 0);
            }
#pragma unroll
            for (int r = 0; r < 4; ++r) {
                float d2 = fmaxf(sqi + sSqJ[J * 16 + 4 * g + r] - 2.0f * sfr[r], 0.0f);
                float e = __expf(-d2);
                dsum += e;
                pw[J][r] = e;
            }
            pk[J][0] = pack2bf(pw[J][0], pw[J][1]);
            pk[J][1] = pack2bf(pw[J][2], pw[J][3]);
        }

        // ---- redistribute to PV A-fragment layout: lane (g,c) needs P[c][8g+e] (e=0..7)
        // word (kt, 2u+p) <- lane 32*(g&1)+16u+c 's pk[J = 2kt + (g>>1)][p]
        uint32_t frag[2][4];
#pragma unroll
        for (int J = 0; J < 4; ++J) {
#pragma unroll
            for (int u = 0; u < 2; ++u) {
#pragma unroll
                for (int p = 0; p < 2; ++p) {
                    uint32_t v = (uint32_t)__shfl((int)pk[J][p], srcbase + u * 16);
                    if ((g >> 1) == (J & 1)) frag[J >> 1][2 * u + p] = v;
                }
            }
        }
        {
            int4 st;
            st.x = (int)frag[0][0]; st.y = (int)frag[0][1];
            st.z = (int)frag[0][2]; st.w = (int)frag[0][3];
            sPA[(w * 2 + 0) * 64 + l] = st;
            st.x = (int)frag[1][0]; st.y = (int)frag[1][1];
            st.z = (int)frag[1][2]; st.w = (int)frag[1][3];
            sPA[(w * 2 + 1) * 64 + l] = st;
        }
        __syncthreads();  // (c) P fragments visible to all waves

        // ---- PV: out += P x z (this wave: rows (2h..2h+1)*16, cols dh*64..+64) ----
#pragma unroll
        for (int ifr = 0; ifr < 2; ++ifr) {
            short8v pa0 = *reinterpret_cast<const short8v*>(&sPA[((2 * h + ifr) * 2 + 0) * 64 + l]);
            short8v pa1 = *reinterpret_cast<const short8v*>(&sPA[((2 * h + ifr) * 2 + 1) * 64 + l]);
#pragma unroll
            for (int nt = 0; nt < 4; ++nt) {
                short8v z0 = *reinterpret_cast<const short8v*>(&sZ[(0 * 8 + dh * 4 + nt) * 64 + l]);
                short8v z1 = *reinterpret_cast<const short8v*>(&sZ[(1 * 8 + dh * 4 + nt) * 64 + l]);
                accPV[ifr][nt] = __builtin_amdgcn_mfma_f32_16x16x32_bf16(pa0, z0, accPV[ifr][nt], 0, 0, 0);
                accPV[ifr][nt] = __builtin_amdgcn_mfma_f32_16x16x32_bf16(pa1, z1, accPV[ifr][nt], 0, 0, 0);
            }
        }
    }

    // dsum: lane (g,c) holds partial row-sum for row w*16 + c over its j-subset;
    // reduce across the 4 g-groups (same c).
    dsum += __shfl_xor(dsum, 16);
    dsum += __shfl_xor(dsum, 32);

    if (njs == 1) {
        if (g == 0) sDen[w * 16 + c] = dsum;
        __syncthreads();
#pragma unroll
        for (int ifr = 0; ifr < 2; ++ifr) {
#pragma unroll
            for (int r = 0; r < 4; ++r) {
                int iloc = (2 * h + ifr) * 16 + g * 4 + r;
                float inv = 1.0f / sDen[iloc];
                size_t row = (size_t)(b * NN + ib + iloc);
#pragma unroll
                for (int nt = 0; nt < 4; ++nt)
                    outnum[row * DD + dh * 64 + nt * 16 + c] = accPV[ifr][nt][r] * inv;
            }
        }
    } else {
        if (g == 0) den[(size_t)js * BN + b * NN + ib + w * 16 + c] = dsum;
#pragma unroll
        for (int ifr = 0; ifr < 2; ++ifr) {
#pragma unroll
            for (int r = 0; r < 4; ++r) {
                int iloc = (2 * h + ifr) * 16 + g * 4 + r;
                size_t row = (size_t)js * BN + b * NN + ib + iloc;
#pragma unroll
                for (int nt = 0; nt < 4; ++nt)
                    outnum[row * DD + dh * 64 + nt * 16 + c] = accPV[ifr][nt][r];
            }
        }
    }
}

// ---------- reduce kernel (njs > 1): out = sum_js num / sum_js den ----------
__global__ __launch_bounds__(256) void reduce_kernel(const float4* __restrict__ num,
                                                     const float* __restrict__ den,
                                                     float4* __restrict__ out,
                                                     int njs) {
    int i4 = blockIdx.x * 256 + threadIdx.x;  // float4 index into [B*N, D]
    int row = i4 >> 5;
    float4 ns = make_float4(0.f, 0.f, 0.f, 0.f);
    float ds = 0.f;
    for (int js = 0; js < njs; ++js) {
        float4 v = num[(size_t)js * ((size_t)BN * (DD / 4)) + i4];
        ns.x += v.x; ns.y += v.y; ns.z += v.z; ns.w += v.w;
        ds += den[(size_t)js * BN + row];
    }
    float inv = 1.0f / ds;
    out[i4] = make_float4(ns.x * inv, ns.y * inv, ns.z * inv, ns.w * inv);
}

extern "C" void kernel_launch(void* const* d_in, const int* in_sizes, int n_in,
                              void* d_out, int out_size, void* d_ws, size_t ws_size,
                              hipStream_t stream) {
    (void)in_sizes; (void)n_in; (void)out_size;
    const float* emb = (const float*)d_in[0];
    const float* z = (const float*)d_in[1];
    float* out = (float*)d_out;
    float* ws = (float*)d_ws;

    // ws layout (floats): sq[BN] | den[njs*BN] | num[njs*BN*DD] | embq(1M shorts) | zq(2M shorts)
    int njs = (ws_size >= 24ull * 1024 * 1024) ? 2 : 1;

    float* sqw = ws;
    float* denw = ws + BN;
    float* numw = denw + (size_t)njs * BN;
    size_t numFloats = (njs > 1) ? (size_t)njs * BN * DD : 0;
    short* embqw = (short*)(numw + numFloats);
    short* zqw = embqw + (size_t)BB * NN * EE;

    sq_kernel<<<BN / 4, 256, 0, stream>>>(emb, sqw);
    embq_kernel<<<(BB * NN * EE / 8) / 256, 256, 0, stream>>>(emb, embqw);
    zq_kernel<<<BB * 32, 256, 0, stream>>>(z, zqw);

    attn_mfma<<<8 * 32 * njs, 256, 0, stream>>>(embqw, zqw, sqw,
                                                njs == 1 ? out : numw, denw, njs);

    if (njs > 1) {
        reduce_kernel<<<(BN * (DD / 4)) / 256, 256, 0, stream>>>(
            (const float4*)numw, denw, (float4*)out, njs);
    }
}

// Round 5
// 45.734 us; speedup vs baseline: 4.7302x; 1.2354x over previous
//
#include <hip/hip_runtime.h>
#include <hip/hip_bf16.h>

#define BB 8
#define NN 2048
#define EE 64
#define DD 128
#define BN (BB * NN)

typedef __attribute__((ext_vector_type(8))) short short8v;
typedef __attribute__((ext_vector_type(4))) float float4v;

__device__ __forceinline__ short f2bf(float f) {
    __hip_bfloat16 h = __float2bfloat16(f);
    return *reinterpret_cast<short*>(&h);
}
__device__ __forceinline__ uint32_t pack2bf(float a, float b) {
    return (uint32_t)(uint16_t)f2bf(a) | ((uint32_t)(uint16_t)f2bf(b) << 16);
}

// async global->LDS, width 16/4 (wave-uniform LDS base + lane*size semantics;
// our per-thread dst pointers are exactly base + lane*size, so this matches).
#define GLD16(gp, lp)                                                          \
    __builtin_amdgcn_global_load_lds(                                          \
        (const __attribute__((address_space(1))) void*)(gp),                   \
        (__attribute__((address_space(3))) void*)(lp), 16, 0, 0)
#define GLD4(gp, lp)                                                           \
    __builtin_amdgcn_global_load_lds(                                          \
        (const __attribute__((address_space(1))) void*)(gp),                   \
        (__attribute__((address_space(3))) void*)(lp), 4, 0, 0)

// ---------------- fused prep: embq | zq | sq in one launch ----------------
// blocks [0,512): embq  — slot ((b*128+r16)*2+ke)*64+s holds emb[b][r16*16+(s&15)][ke*32+((s>>4)&3)*8+e]
// blocks [512,768): zq  — slot ((b*64+jkt)*8+nt)*64+s holds z[b][jkt*32+((s>>4)&3)*8+e][nt*16+(s&15)]
// blocks [768,1024): sq — sq[row] = ||bf16(emb[row,:])||^2 (16 lanes/row, float4)
__global__ __launch_bounds__(256) void prep_kernel(const float* __restrict__ emb,
                                                   const float* __restrict__ z,
                                                   short* __restrict__ embq,
                                                   short* __restrict__ zq,
                                                   float* __restrict__ sq) {
    __shared__ float zl[64 * 129];
    const int bid = blockIdx.x;
    const int t = threadIdx.x;

    if (bid < 512) {
        int gid = bid * 256 + t;  // 131072 total
        int s = gid & 63;
        int ke = (gid >> 6) & 1;
        int r16 = (gid >> 7) & 127;
        int b = gid >> 14;
        int i = r16 * 16 + (s & 15);
        int e0 = ke * 32 + ((s >> 4) & 3) * 8;
        const float* src = emb + ((size_t)(b * NN + i)) * EE + e0;
        short8v o;
#pragma unroll
        for (int e = 0; e < 8; ++e) o[e] = f2bf(src[e]);
        *reinterpret_cast<short8v*>(embq + (size_t)gid * 8) = o;
    } else if (bid < 768) {
        int v = bid - 512;  // b*32 + jt
        int b = v >> 5;
        int jt = v & 31;
        int jb = jt * 64;
#pragma unroll
        for (int k = 0; k < 8; ++k) {
            int idx = t + k * 256;  // float4 units over [64][128]
            int jl = idx >> 5, c4 = idx & 31;
            float4 w = reinterpret_cast<const float4*>(z + ((size_t)(b * NN + jb + jl)) * DD)[c4];
            float* p = &zl[jl * 129 + c4 * 4];
            p[0] = w.x; p[1] = w.y; p[2] = w.z; p[3] = w.w;
        }
        __syncthreads();
#pragma unroll
        for (int k = 0; k < 4; ++k) {
            int sid = t + k * 256;
            int blk = sid >> 6, s = sid & 63;
            int ktl = blk >> 3, nt = blk & 7;
            int d = nt * 16 + (s & 15);
            int jl = ktl * 32 + ((s >> 4) & 3) * 8;
            short8v o;
#pragma unroll
            for (int e = 0; e < 8; ++e) o[e] = f2bf(zl[(jl + e) * 129 + d]);
            *reinterpret_cast<short8v*>(zq + ((size_t)((b * 64 + jt * 2 + ktl) * 8 + nt) * 64 + s) * 8) = o;
        }
    } else {
        int v = bid - 768;  // 64 rows per block
        int q = t & 15;
#pragma unroll
        for (int p = 0; p < 4; ++p) {
            int row = v * 64 + p * 16 + (t >> 4);
            float4 rv = reinterpret_cast<const float4*>(emb + (size_t)row * EE)[q];
            float a0 = __bfloat162float(__float2bfloat16(rv.x));
            float a1 = __bfloat162float(__float2bfloat16(rv.y));
            float a2 = __bfloat162float(__float2bfloat16(rv.z));
            float a3 = __bfloat162float(__float2bfloat16(rv.w));
            float s2 = a0 * a0 + a1 * a1 + a2 * a2 + a3 * a3;
#pragma unroll
            for (int off = 1; off < 16; off <<= 1) s2 += __shfl_xor(s2, off);
            if (q == 0) sq[row] = s2;
        }
    }
}

// ---------------- main MFMA attention, 1 barrier/tile pipeline ----------------
// grid: bid = (js*32 + it)*8 + b  (XCD x pinned to batch x). 4 waves/block.
// Wave w owns rows w*16..w*16+15 for BOTH QK and PV (P stays wave-local).
// QK (swapped): lane (g,c) holds S[i=w*16+c][j=16J+4g+r]; same-wave LDS transpose
// (XOR-swizzled) produces PV A-fragments; PV covers full d=128 per wave.
__global__ __launch_bounds__(256, 2) void attn_mfma(const short* __restrict__ embq,
                                                    const short* __restrict__ zq,
                                                    const float* __restrict__ sq,
                                                    float* __restrict__ outnum,
                                                    float* __restrict__ den,
                                                    int njs) {
    __shared__ int4 sEmbI[512];       // 8KB  [ifr(4)][ke(2)][64]
    __shared__ int4 sEmbJ[2][512];    // 16KB dbuf
    __shared__ int4 sZ[2][1024];      // 32KB dbuf [kt(2)][nt(8)][64]
    __shared__ short sPT[4][1024];    // 8KB per-wave P^T scratch [i=16][j=64], XOR-swizzled
    __shared__ float sSqJ[2][64];     // dbuf

    const int t = threadIdx.x;
    const int bid = blockIdx.x;
    const int b = bid & 7;
    const int q = bid >> 3;
    const int it = q & 31;
    const int js = q >> 5;
    const int ib = it * 64;
    const int w = t >> 6;
    const int l = t & 63;
    const int g = (l >> 4) & 3;
    const int c = l & 15;

    const int4* embqI4 = (const int4*)embq;
    const int4* zqI4 = (const int4*)zq;
    const float* sqB = sq + b * NN;

    const int ntiles = 32 / njs;
    const int jt0 = js * ntiles;
    const int jtEnd = jt0 + ntiles;

    // prologue: issue embI + tile-0 staging, then one drain barrier
    {
        const int4* srcI = embqI4 + (size_t)(b * 128 + (ib >> 4)) * 2 * 64;
        GLD16(srcI + t, &sEmbI[t]);
        GLD16(srcI + t + 256, &sEmbI[t + 256]);
        const int4* srcJ = embqI4 + (size_t)(b * 128 + jt0 * 4) * 2 * 64;
        GLD16(srcJ + t, &sEmbJ[0][t]);
        GLD16(srcJ + t + 256, &sEmbJ[0][t + 256]);
        const int4* srcZ = zqI4 + (size_t)((b * 64 + jt0 * 2) * 8) * 64;
#pragma unroll
        for (int k = 0; k < 4; ++k) GLD16(srcZ + t + k * 256, &sZ[0][t + k * 256]);
        if (t < 64) GLD4(sqB + jt0 * 64 + t, &sSqJ[0][t]);
    }
    __syncthreads();  // drains vmcnt -> everything staged

    short8v qkB[2];  // this wave's embI fragments (B operand of swapped QK)
    qkB[0] = *reinterpret_cast<const short8v*>(&sEmbI[(w * 2 + 0) * 64 + l]);
    qkB[1] = *reinterpret_cast<const short8v*>(&sEmbI[(w * 2 + 1) * 64 + l]);
    const float sqi = sqB[ib + w * 16 + c];

    float dsum = 0.f;
    float4v acc[8];
#pragma unroll
    for (int nt = 0; nt < 8; ++nt) acc[nt] = (float4v){0.f, 0.f, 0.f, 0.f};

    char* ptw = (char*)&sPT[w][0];
    const int woffBase = (c * 128 + g * 8) ^ ((c & 7) << 4);
    const int roffBase = (c * 128 + g * 16) ^ ((c & 7) << 4);

    int cur = 0;
    for (int jt = jt0; jt < jtEnd; ++jt, cur ^= 1) {
        // prefetch next tile into the other buffer (clamped; drained at end-bar)
        {
            int jn = (jt + 1 < jtEnd) ? jt + 1 : jt;
            int nxt = cur ^ 1;
            const int4* srcJ = embqI4 + (size_t)(b * 128 + jn * 4) * 2 * 64;
            GLD16(srcJ + t, &sEmbJ[nxt][t]);
            GLD16(srcJ + t + 256, &sEmbJ[nxt][t + 256]);
            const int4* srcZ = zqI4 + (size_t)((b * 64 + jn * 2) * 8) * 64;
#pragma unroll
            for (int k = 0; k < 4; ++k) GLD16(srcZ + t + k * 256, &sZ[nxt][t + k * 256]);
            if (t < 64) GLD4(sqB + jn * 64 + t, &sSqJ[nxt][t]);
        }

        // ---- QK (swapped): S^T tiles; exp; pack; same-wave LDS transpose write ----
#pragma unroll
        for (int J = 0; J < 4; ++J) {
            float4v sfr = (float4v){0.f, 0.f, 0.f, 0.f};
#pragma unroll
            for (int ke = 0; ke < 2; ++ke) {
                short8v afrag = *reinterpret_cast<const short8v*>(&sEmbJ[cur][(J * 2 + ke) * 64 + l]);
                sfr = __builtin_amdgcn_mfma_f32_16x16x32_bf16(afrag, qkB[ke], sfr, 0, 0, 0);
            }
            float pw[4];
#pragma unroll
            for (int r = 0; r < 4; ++r) {
                float d2 = fmaxf(sqi + sSqJ[cur][J * 16 + 4 * g + r] - 2.0f * sfr[r], 0.0f);
                pw[r] = __expf(-d2);
                dsum += pw[r];
            }
            uint32_t pk0 = pack2bf(pw[0], pw[1]);
            uint32_t pk1 = pack2bf(pw[2], pw[3]);
            *reinterpret_cast<unsigned long long*>(ptw + (woffBase ^ (J * 32))) =
                (unsigned long long)pk0 | ((unsigned long long)pk1 << 32);
        }

        // ---- PV: read own P^T fragments (same wave, no barrier) and MFMA over d ----
        short8v pa0 = *reinterpret_cast<const short8v*>(ptw + roffBase);
        short8v pa1 = *reinterpret_cast<const short8v*>(ptw + (roffBase ^ 64));
#pragma unroll
        for (int nt = 0; nt < 8; ++nt) {
            short8v z0 = *reinterpret_cast<const short8v*>(&sZ[cur][(0 * 8 + nt) * 64 + l]);
            short8v z1 = *reinterpret_cast<const short8v*>(&sZ[cur][(1 * 8 + nt) * 64 + l]);
            acc[nt] = __builtin_amdgcn_mfma_f32_16x16x32_bf16(pa0, z0, acc[nt], 0, 0, 0);
            acc[nt] = __builtin_amdgcn_mfma_f32_16x16x32_bf16(pa1, z1, acc[nt], 0, 0, 0);
        }

        __syncthreads();  // single sync point: drains prefetch, guards buffer reuse
    }

    // dsum: reduce over g-groups -> every lane holds dsum[row c]
    dsum += __shfl_xor(dsum, 16);
    dsum += __shfl_xor(dsum, 32);

    if (njs == 1) {
        float invr[4];
#pragma unroll
        for (int r = 0; r < 4; ++r) invr[r] = 1.0f / __shfl(dsum, 4 * g + r);
#pragma unroll
        for (int r = 0; r < 4; ++r) {
            size_t row = (size_t)(b * NN + ib + w * 16 + 4 * g + r);
#pragma unroll
            for (int nt = 0; nt < 8; ++nt)
                outnum[row * DD + nt * 16 + c] = acc[nt][r] * invr[r];
        }
    } else {
        if (l < 16) den[(size_t)js * BN + b * NN + ib + w * 16 + l] = dsum;
#pragma unroll
        for (int r = 0; r < 4; ++r) {
            size_t row = (size_t)js * BN + b * NN + ib + w * 16 + 4 * g + r;
#pragma unroll
            for (int nt = 0; nt < 8; ++nt)
                outnum[row * DD + nt * 16 + c] = acc[nt][r];
        }
    }
}

// ---------------- reduce (njs > 1): out = sum_js num / sum_js den ----------------
__global__ __launch_bounds__(256) void reduce_kernel(const float4* __restrict__ num,
                                                     const float* __restrict__ den,
                                                     float4* __restrict__ out,
                                                     int njs) {
    int i4 = blockIdx.x * 256 + threadIdx.x;  // float4 index into [B*N, D]
    int row = i4 >> 5;
    float4 ns = make_float4(0.f, 0.f, 0.f, 0.f);
    float ds = 0.f;
    for (int js = 0; js < njs; ++js) {
        float4 v = num[(size_t)js * ((size_t)BN * (DD / 4)) + i4];
        ns.x += v.x; ns.y += v.y; ns.z += v.z; ns.w += v.w;
        ds += den[(size_t)js * BN + row];
    }
    float inv = 1.0f / ds;
    out[i4] = make_float4(ns.x * inv, ns.y * inv, ns.z * inv, ns.w * inv);
}

extern "C" void kernel_launch(void* const* d_in, const int* in_sizes, int n_in,
                              void* d_out, int out_size, void* d_ws, size_t ws_size,
                              hipStream_t stream) {
    (void)in_sizes; (void)n_in; (void)out_size;
    const float* emb = (const float*)d_in[0];
    const float* z = (const float*)d_in[1];
    float* out = (float*)d_out;
    float* ws = (float*)d_ws;

    // ws layout (floats): sq[BN] | den[njs*BN] | num[njs*BN*DD] | embq(1M shorts) | zq(2M shorts)
    int njs = (ws_size >= 24ull * 1024 * 1024) ? 2 : 1;

    float* sqw = ws;
    float* denw = ws + BN;
    float* numw = denw + (size_t)njs * BN;
    size_t numFloats = (njs > 1) ? (size_t)njs * BN * DD : 0;
    short* embqw = (short*)(numw + numFloats);
    short* zqw = embqw + (size_t)BB * NN * EE;

    prep_kernel<<<1024, 256, 0, stream>>>(emb, z, embqw, zqw, sqw);

    attn_mfma<<<8 * 32 * njs, 256, 0, stream>>>(embqw, zqw, sqw,
                                                njs == 1 ? out : numw, denw, njs);

    if (njs > 1) {
        reduce_kernel<<<(BN * (DD / 4)) / 256, 256, 0, stream>>>(
            (const float4*)numw, denw, (float4*)out, njs);
    }
}

// Round 6
// 35.938 us; speedup vs baseline: 6.0195x; 1.2726x over previous
//
#include <hip/hip_runtime.h>
#include <hip/hip_bf16.h>

#define BB 8
#define NN 2048
#define EE 64
#define DD 128
#define BN (BB * NN)

typedef __attribute__((ext_vector_type(8))) short short8v;
typedef __attribute__((ext_vector_type(4))) float float4v;

__device__ __forceinline__ short f2bf(float f) {
    __hip_bfloat16 h = __float2bfloat16(f);
    return *reinterpret_cast<short*>(&h);
}
__device__ __forceinline__ uint32_t pack2bf(float a, float b) {
    return (uint32_t)(uint16_t)f2bf(a) | ((uint32_t)(uint16_t)f2bf(b) << 16);
}

#define GLD16(gp, lp)                                                          \
    __builtin_amdgcn_global_load_lds(                                          \
        (const __attribute__((address_space(1))) void*)(gp),                   \
        (__attribute__((address_space(3))) void*)(lp), 16, 0, 0)
#define GLD4(gp, lp)                                                           \
    __builtin_amdgcn_global_load_lds(                                          \
        (const __attribute__((address_space(1))) void*)(gp),                   \
        (__attribute__((address_space(3))) void*)(lp), 4, 0, 0)

// ---------------- fused prep: embq | zq | sq ----------------
// blocks [0,512): embq  — slot ((b*128+r16)*2+ke)*64+s holds emb[b][r16*16+(s&15)][ke*32+((s>>4)&3)*8+e]
// blocks [512,768): zq  — slot ((b*64+jkt)*8+nt)*64+s holds z[b][jkt*32+((s>>4)&3)*8+e][nt*16+(s&15)]
// blocks [768,1024): sq — sq[row] = ||bf16(emb[row,:])||^2
__global__ __launch_bounds__(256) void prep_kernel(const float* __restrict__ emb,
                                                   const float* __restrict__ z,
                                                   short* __restrict__ embq,
                                                   short* __restrict__ zq,
                                                   float* __restrict__ sq) {
    __shared__ float zl[64 * 129];
    const int bid = blockIdx.x;
    const int t = threadIdx.x;

    if (bid < 512) {
        int gid = bid * 256 + t;
        int s = gid & 63;
        int ke = (gid >> 6) & 1;
        int r16 = (gid >> 7) & 127;
        int b = gid >> 14;
        int i = r16 * 16 + (s & 15);
        int e0 = ke * 32 + ((s >> 4) & 3) * 8;
        const float4* src = reinterpret_cast<const float4*>(emb + ((size_t)(b * NN + i)) * EE + e0);
        float4 v0 = src[0], v1 = src[1];
        short8v o;
        o[0] = f2bf(v0.x); o[1] = f2bf(v0.y); o[2] = f2bf(v0.z); o[3] = f2bf(v0.w);
        o[4] = f2bf(v1.x); o[5] = f2bf(v1.y); o[6] = f2bf(v1.z); o[7] = f2bf(v1.w);
        *reinterpret_cast<short8v*>(embq + (size_t)gid * 8) = o;
    } else if (bid < 768) {
        int v = bid - 512;  // b*32 + jt
        int b = v >> 5;
        int jt = v & 31;
        int jb = jt * 64;
#pragma unroll
        for (int k = 0; k < 8; ++k) {
            int idx = t + k * 256;
            int jl = idx >> 5, c4 = idx & 31;
            float4 w = reinterpret_cast<const float4*>(z + ((size_t)(b * NN + jb + jl)) * DD)[c4];
            float* p = &zl[jl * 129 + c4 * 4];
            p[0] = w.x; p[1] = w.y; p[2] = w.z; p[3] = w.w;
        }
        __syncthreads();
#pragma unroll
        for (int k = 0; k < 4; ++k) {
            int sid = t + k * 256;
            int blk = sid >> 6, s = sid & 63;
            int ktl = blk >> 3, nt = blk & 7;
            int d = nt * 16 + (s & 15);
            int jl = ktl * 32 + ((s >> 4) & 3) * 8;
            short8v o;
#pragma unroll
            for (int e = 0; e < 8; ++e) o[e] = f2bf(zl[(jl + e) * 129 + d]);
            *reinterpret_cast<short8v*>(zq + ((size_t)((b * 64 + jt * 2 + ktl) * 8 + nt) * 64 + s) * 8) = o;
        }
    } else {
        int v = bid - 768;
        int q = t & 15;
#pragma unroll
        for (int p = 0; p < 4; ++p) {
            int row = v * 64 + p * 16 + (t >> 4);
            float4 rv = reinterpret_cast<const float4*>(emb + (size_t)row * EE)[q];
            float a0 = __bfloat162float(__float2bfloat16(rv.x));
            float a1 = __bfloat162float(__float2bfloat16(rv.y));
            float a2 = __bfloat162float(__float2bfloat16(rv.z));
            float a3 = __bfloat162float(__float2bfloat16(rv.w));
            float s2 = a0 * a0 + a1 * a1 + a2 * a2 + a3 * a3;
#pragma unroll
            for (int off = 1; off < 16; off <<= 1) s2 += __shfl_xor(s2, off);
            if (q == 0) sq[row] = s2;
        }
    }
}

// ---------------- main MFMA attention ----------------
// grid: bid = ((js*16 + it))*8 + b (XCD-pinned batch). 4 waves; wave owns 32 rows (2 groups).
// QK (swapped): lane (g,c), group m holds S[i=w*32+m*16+c][j=J*16+4g+r].
// P via same-wave XOR-swizzled LDS transpose; PV B-operand (zq) read direct from global (L2).
// PV skipped when all p < 1e-6 in tile (bounded error <= 2048e-6*|z| ~ 0.01).
__global__ __launch_bounds__(256, 2) void attn_mfma(const short* __restrict__ embq,
                                                    const short* __restrict__ zq,
                                                    const float* __restrict__ sq,
                                                    float* __restrict__ outnum,
                                                    float* __restrict__ den,
                                                    int njs) {
    __shared__ short sU[4][2048];   // 16KB union: embI staging (prologue) -> per-wave P^T scratch
    __shared__ int4 sEmbJ[2][512];  // 16KB dbuf [jfr(4)][ke(2)][64]
    __shared__ float sSqJ[2][64];

    const int t = threadIdx.x;
    const int bid = blockIdx.x;
    const int b = bid & 7;
    const int q = bid >> 3;
    const int it = q & 15;
    const int js = q >> 4;
    const int ib = it * 128;
    const int w = t >> 6;
    const int l = t & 63;
    const int g = (l >> 4) & 3;
    const int c = l & 15;

    const int4* embqI4 = (const int4*)embq;
    const short8v* zq8 = (const short8v*)zq;
    const float* sqB = sq + b * NN;

    const int ntiles = 32 / njs;
    const int jt0 = js * ntiles;
    const int jtEnd = jt0 + ntiles;

    int4* sUi = (int4*)&sU[0][0];

    // prologue: stage embI (128 rows -> union) + tile0 embJ + sq; drain once
    {
        const int4* srcI = embqI4 + (size_t)(b * 128 + it * 8) * 2 * 64;
#pragma unroll
        for (int k = 0; k < 4; ++k) GLD16(srcI + t + k * 256, sUi + t + k * 256);
        const int4* srcJ = embqI4 + (size_t)(b * 128 + jt0 * 4) * 2 * 64;
        GLD16(srcJ + t, &sEmbJ[0][t]);
        GLD16(srcJ + t + 256, &sEmbJ[0][t + 256]);
        if (t < 64) GLD4(sqB + jt0 * 64 + t, &sSqJ[0][t]);
    }
    __syncthreads();

    // wave's embI fragments (B operand of swapped QK): group m, ke
    short8v qkB[2][2];
#pragma unroll
    for (int m = 0; m < 2; ++m)
#pragma unroll
        for (int ke = 0; ke < 2; ++ke)
            qkB[m][ke] = *reinterpret_cast<const short8v*>(&sUi[((w * 2 + m) * 2 + ke) * 64 + l]);
    float sqi[2];
#pragma unroll
    for (int m = 0; m < 2; ++m) sqi[m] = sqB[ib + w * 32 + m * 16 + c];

    float dsum[2] = {0.f, 0.f};
    float4v acc[2][8];
#pragma unroll
    for (int m = 0; m < 2; ++m)
#pragma unroll
        for (int nt = 0; nt < 8; ++nt) acc[m][nt] = (float4v){0.f, 0.f, 0.f, 0.f};

    char* ptw = (char*)&sU[w][0];
    const int swz = (c & 7) << 4;

    int cur = 0;
    for (int jt = jt0; jt < jtEnd; ++jt, cur ^= 1) {
        {   // prefetch next embJ + sq
            int jn = (jt + 1 < jtEnd) ? jt + 1 : jt;
            int nxt = cur ^ 1;
            const int4* srcJ = embqI4 + (size_t)(b * 128 + jn * 4) * 2 * 64;
            GLD16(srcJ + t, &sEmbJ[nxt][t]);
            GLD16(srcJ + t + 256, &sEmbJ[nxt][t + 256]);
            if (t < 64) GLD4(sqB + jn * 64 + t, &sSqJ[nxt][t]);
        }

        // ---- QK (swapped): S^T tiles, exp, pack (buffered in regs) ----
        uint32_t pk[2][4][2];
        float d2min = 1e30f;
#pragma unroll
        for (int J = 0; J < 4; ++J) {
            short8v afrag[2];
            afrag[0] = *reinterpret_cast<const short8v*>(&sEmbJ[cur][(J * 2 + 0) * 64 + l]);
            afrag[1] = *reinterpret_cast<const short8v*>(&sEmbJ[cur][(J * 2 + 1) * 64 + l]);
#pragma unroll
            for (int m = 0; m < 2; ++m) {
                float4v sfr = (float4v){0.f, 0.f, 0.f, 0.f};
                sfr = __builtin_amdgcn_mfma_f32_16x16x32_bf16(afrag[0], qkB[m][0], sfr, 0, 0, 0);
                sfr = __builtin_amdgcn_mfma_f32_16x16x32_bf16(afrag[1], qkB[m][1], sfr, 0, 0, 0);
                float pw[4];
#pragma unroll
                for (int r = 0; r < 4; ++r) {
                    float d2 = fmaxf(sqi[m] + sSqJ[cur][J * 16 + 4 * g + r] - 2.0f * sfr[r], 0.0f);
                    d2min = fminf(d2min, d2);
                    pw[r] = __expf(-d2);
                    dsum[m] += pw[r];
                }
                pk[m][J][0] = pack2bf(pw[0], pw[1]);
                pk[m][J][1] = pack2bf(pw[2], pw[3]);
            }
        }

        // ---- PV only if some weight is non-negligible (p >= 1e-6) ----
        if (!__all(d2min > 13.8f)) {
#pragma unroll
            for (int m = 0; m < 2; ++m) {
                const int woff = (m * 2048 + c * 128 + g * 8) ^ swz;
#pragma unroll
                for (int J = 0; J < 4; ++J)
                    *reinterpret_cast<unsigned long long*>(ptw + (woff ^ (J * 32))) =
                        (unsigned long long)pk[m][J][0] | ((unsigned long long)pk[m][J][1] << 32);
            }
            short8v pa[2][2];
#pragma unroll
            for (int m = 0; m < 2; ++m)
#pragma unroll
                for (int kt = 0; kt < 2; ++kt)
                    pa[m][kt] = *reinterpret_cast<const short8v*>(
                        ptw + ((m * 2048 + c * 128 + kt * 64 + g * 16) ^ swz));
#pragma unroll
            for (int nt = 0; nt < 8; ++nt) {
                short8v z0 = zq8[(size_t)((b * 64 + jt * 2 + 0) * 8 + nt) * 64 + l];
                short8v z1 = zq8[(size_t)((b * 64 + jt * 2 + 1) * 8 + nt) * 64 + l];
#pragma unroll
                for (int m = 0; m < 2; ++m) {
                    acc[m][nt] = __builtin_amdgcn_mfma_f32_16x16x32_bf16(pa[m][0], z0, acc[m][nt], 0, 0, 0);
                    acc[m][nt] = __builtin_amdgcn_mfma_f32_16x16x32_bf16(pa[m][1], z1, acc[m][nt], 0, 0, 0);
                }
            }
        }

        __syncthreads();  // single sync: guards sEmbJ dbuf reuse + drains prefetch
    }

    // dsum reduce over g-groups -> all lanes hold row (m, c) sums
#pragma unroll
    for (int m = 0; m < 2; ++m) {
        dsum[m] += __shfl_xor(dsum[m], 16);
        dsum[m] += __shfl_xor(dsum[m], 32);
    }

    if (njs == 1) {
#pragma unroll
        for (int m = 0; m < 2; ++m) {
            float invr[4];
#pragma unroll
            for (int r = 0; r < 4; ++r) invr[r] = 1.0f / __shfl(dsum[m], 4 * g + r);
#pragma unroll
            for (int r = 0; r < 4; ++r) {
                size_t row = (size_t)(b * NN + ib + w * 32 + m * 16 + 4 * g + r);
#pragma unroll
                for (int nt = 0; nt < 8; ++nt)
                    outnum[row * DD + nt * 16 + c] = acc[m][nt][r] * invr[r];
            }
        }
    } else {
        if (l < 16) {
            den[(size_t)js * BN + b * NN + ib + w * 32 + l] = dsum[0];
            den[(size_t)js * BN + b * NN + ib + w * 32 + 16 + l] = dsum[1];
        }
        // skip num writes when this wave's whole j-slice carries no mass
        if (!__all(fmaxf(dsum[0], dsum[1]) < 1e-6f)) {
#pragma unroll
            for (int m = 0; m < 2; ++m)
#pragma unroll
                for (int r = 0; r < 4; ++r) {
                    size_t row = (size_t)js * BN + b * NN + ib + w * 32 + m * 16 + 4 * g + r;
#pragma unroll
                    for (int nt = 0; nt < 8; ++nt)
                        outnum[row * DD + nt * 16 + c] = acc[m][nt][r];
                }
        }
    }
}

// ---------------- reduce: out = sum_js num / sum_js den, num reads gated by den ----------------
__global__ __launch_bounds__(256) void reduce_kernel(const float4* __restrict__ num,
                                                     const float* __restrict__ den,
                                                     float4* __restrict__ out,
                                                     int njs) {
    int i4 = blockIdx.x * 256 + threadIdx.x;
    int row = i4 >> 5;
    float4 ns = make_float4(0.f, 0.f, 0.f, 0.f);
    float ds = 0.f;
    for (int js = 0; js < njs; ++js) {
        float dj = den[(size_t)js * BN + row];
        ds += dj;
        if (dj >= 1e-6f) {  // slices below tau were never written (and contribute < 5e-6)
            float4 v = num[(size_t)js * ((size_t)BN * (DD / 4)) + i4];
            ns.x += v.x; ns.y += v.y; ns.z += v.z; ns.w += v.w;
        }
    }
    float inv = 1.0f / ds;
    out[i4] = make_float4(ns.x * inv, ns.y * inv, ns.z * inv, ns.w * inv);
}

extern "C" void kernel_launch(void* const* d_in, const int* in_sizes, int n_in,
                              void* d_out, int out_size, void* d_ws, size_t ws_size,
                              hipStream_t stream) {
    (void)in_sizes; (void)n_in; (void)out_size;
    const float* emb = (const float*)d_in[0];
    const float* z = (const float*)d_in[1];
    float* out = (float*)d_out;
    float* ws = (float*)d_ws;

    // ws layout (floats): sq[BN] | den[njs*BN] | num[njs*BN*DD] | embq(1M shorts) | zq(2M shorts)
    int njs = 1;
    if (ws_size >= 40ull * 1024 * 1024) njs = 4;
    else if (ws_size >= 24ull * 1024 * 1024) njs = 2;

    float* sqw = ws;
    float* denw = ws + BN;
    float* numw = denw + (size_t)njs * BN;
    size_t numFloats = (njs > 1) ? (size_t)njs * BN * DD : 0;
    short* embqw = (short*)(numw + numFloats);
    short* zqw = embqw + (size_t)BB * NN * EE;

    prep_kernel<<<1024, 256, 0, stream>>>(emb, z, embqw, zqw, sqw);

    attn_mfma<<<8 * 16 * njs, 256, 0, stream>>>(embqw, zqw, sqw,
                                                njs == 1 ? out : numw, denw, njs);

    if (njs > 1) {
        reduce_kernel<<<(BN * (DD / 4)) / 256, 256, 0, stream>>>(
            (const float4*)numw, denw, (float4*)out, njs);
    }
}

// Round 7
// 29.460 us; speedup vs baseline: 7.3430x; 1.2199x over previous
//
#include <hip/hip_runtime.h>
#include <hip/hip_bf16.h>

#define BB 8
#define NN 2048
#define EE 64
#define DD 128
#define BN (BB * NN)

typedef __attribute__((ext_vector_type(8))) short short8v;
typedef __attribute__((ext_vector_type(4))) float float4v;

__device__ __forceinline__ short f2bf(float f) {
    __hip_bfloat16 h = __float2bfloat16(f);
    return *reinterpret_cast<short*>(&h);
}
__device__ __forceinline__ uint32_t pack2bf(float a, float b) {
    return (uint32_t)(uint16_t)f2bf(a) | ((uint32_t)(uint16_t)f2bf(b) << 16);
}

#define GLD16(gp, lp)                                                          \
    __builtin_amdgcn_global_load_lds(                                          \
        (const __attribute__((address_space(1))) void*)(gp),                   \
        (__attribute__((address_space(3))) void*)(lp), 16, 0, 0)
#define GLD4(gp, lp)                                                           \
    __builtin_amdgcn_global_load_lds(                                          \
        (const __attribute__((address_space(1))) void*)(gp),                   \
        (__attribute__((address_space(3))) void*)(lp), 4, 0, 0)

// ---------------- fused prep: embq | zq | sq ----------------
// blocks [0,512): embq  — slot ((b*128+r16)*2+ke)*64+s holds emb[b][r16*16+(s&15)][ke*32+((s>>4)&3)*8+e]
// blocks [512,768): zq  — slot ((b*64+jkt)*8+nt)*64+s holds z[b][jkt*32+((s>>4)&3)*8+e][nt*16+(s&15)]
// blocks [768,1024): sq — sq[row] = ||bf16(emb[row,:])||^2
__global__ __launch_bounds__(256) void prep_kernel(const float* __restrict__ emb,
                                                   const float* __restrict__ z,
                                                   short* __restrict__ embq,
                                                   short* __restrict__ zq,
                                                   float* __restrict__ sq) {
    __shared__ float zl[64 * 129];
    const int bid = blockIdx.x;
    const int t = threadIdx.x;

    if (bid < 512) {
        int gid = bid * 256 + t;
        int s = gid & 63;
        int ke = (gid >> 6) & 1;
        int r16 = (gid >> 7) & 127;
        int b = gid >> 14;
        int i = r16 * 16 + (s & 15);
        int e0 = ke * 32 + ((s >> 4) & 3) * 8;
        const float4* src = reinterpret_cast<const float4*>(emb + ((size_t)(b * NN + i)) * EE + e0);
        float4 v0 = src[0], v1 = src[1];
        short8v o;
        o[0] = f2bf(v0.x); o[1] = f2bf(v0.y); o[2] = f2bf(v0.z); o[3] = f2bf(v0.w);
        o[4] = f2bf(v1.x); o[5] = f2bf(v1.y); o[6] = f2bf(v1.z); o[7] = f2bf(v1.w);
        *reinterpret_cast<short8v*>(embq + (size_t)gid * 8) = o;
    } else if (bid < 768) {
        int v = bid - 512;  // b*32 + jt
        int b = v >> 5;
        int jt = v & 31;
        int jb = jt * 64;
#pragma unroll
        for (int k = 0; k < 8; ++k) {
            int idx = t + k * 256;
            int jl = idx >> 5, c4 = idx & 31;
            float4 w = reinterpret_cast<const float4*>(z + ((size_t)(b * NN + jb + jl)) * DD)[c4];
            float* p = &zl[jl * 129 + c4 * 4];
            p[0] = w.x; p[1] = w.y; p[2] = w.z; p[3] = w.w;
        }
        __syncthreads();
#pragma unroll
        for (int k = 0; k < 4; ++k) {
            int sid = t + k * 256;
            int blk = sid >> 6, s = sid & 63;
            int ktl = blk >> 3, nt = blk & 7;
            int d = nt * 16 + (s & 15);
            int jl = ktl * 32 + ((s >> 4) & 3) * 8;
            short8v o;
#pragma unroll
            for (int e = 0; e < 8; ++e) o[e] = f2bf(zl[(jl + e) * 129 + d]);
            *reinterpret_cast<short8v*>(zq + ((size_t)((b * 64 + jt * 2 + ktl) * 8 + nt) * 64 + s) * 8) = o;
        }
    } else {
        int v = bid - 768;
        int q = t & 15;
#pragma unroll
        for (int p = 0; p < 4; ++p) {
            int row = v * 64 + p * 16 + (t >> 4);
            float4 rv = reinterpret_cast<const float4*>(emb + (size_t)row * EE)[q];
            float a0 = __bfloat162float(__float2bfloat16(rv.x));
            float a1 = __bfloat162float(__float2bfloat16(rv.y));
            float a2 = __bfloat162float(__float2bfloat16(rv.z));
            float a3 = __bfloat162float(__float2bfloat16(rv.w));
            float s2 = a0 * a0 + a1 * a1 + a2 * a2 + a3 * a3;
#pragma unroll
            for (int off = 1; off < 16; off <<= 1) s2 += __shfl_xor(s2, off);
            if (q == 0) sq[row] = s2;
        }
    }
}

// ---------------- main MFMA attention ----------------
// grid: bid = ((js*32 + it))*8 + b (XCD-pinned batch). 4 waves; wave owns 16 rows.
// QK (swapped): lane (g,c) holds S[i=w*16+c][j=J*16+4g+r] for J=0..3.
// Vote-before-exp: per-J wave vote (all d2 > 13.8 => all p < 1e-6) skips exp/pack;
// whole-tile vote skips PV. Bounded truncation: den/num error < 2e-3 (out err < ~0.01).
// P via same-wave XOR-swizzled LDS transpose in a wave-private 2KB union region.
__global__ __launch_bounds__(256, 4) void attn_mfma(const short* __restrict__ embq,
                                                    const short* __restrict__ zq,
                                                    const float* __restrict__ sq,
                                                    float* __restrict__ outnum,
                                                    float* __restrict__ den,
                                                    int njs) {
    __shared__ short sU[4][1024];   // 8KB union: embI staging (prologue) -> per-wave P^T
    __shared__ int4 sEmbJ[2][512];  // 16KB dbuf [jfr(4)][ke(2)][64]
    __shared__ float sSqJ[2][64];

    const int t = threadIdx.x;
    const int bid = blockIdx.x;
    const int b = bid & 7;
    const int q = bid >> 3;
    const int it = q & 31;
    const int js = q >> 5;
    const int ib = it * 64;
    const int w = t >> 6;
    const int l = t & 63;
    const int g = (l >> 4) & 3;
    const int c = l & 15;

    const int4* embqI4 = (const int4*)embq;
    const short8v* zq8 = (const short8v*)zq;
    const float* sqB = sq + b * NN;

    const int ntiles = 32 / njs;
    const int jt0 = js * ntiles;
    const int jtEnd = jt0 + ntiles;

    int4* sUi = (int4*)&sU[0][0];

    // prologue: stage embI (64 rows) into union + tile0 embJ + sq; drain once
    {
        const int4* srcI = embqI4 + (size_t)(b * 128 + it * 4) * 2 * 64;
        GLD16(srcI + t, sUi + t);
        GLD16(srcI + t + 256, sUi + t + 256);
        const int4* srcJ = embqI4 + (size_t)(b * 128 + jt0 * 4) * 2 * 64;
        GLD16(srcJ + t, &sEmbJ[0][t]);
        GLD16(srcJ + t + 256, &sEmbJ[0][t + 256]);
        if (t < 64) GLD4(sqB + jt0 * 64 + t, &sSqJ[0][t]);
    }
    __syncthreads();

    // wave w reads exactly its own sU[w] 2KB region (slots (w*2+ke)*64+l), so the
    // P^T overwrite below is same-wave-ordered — no extra barrier needed.
    short8v qkB[2];
    qkB[0] = *reinterpret_cast<const short8v*>(&sUi[(w * 2 + 0) * 64 + l]);
    qkB[1] = *reinterpret_cast<const short8v*>(&sUi[(w * 2 + 1) * 64 + l]);
    const float sqi = sqB[ib + w * 16 + c];

    float dsum = 0.f;
    float4v acc[8];
#pragma unroll
    for (int nt = 0; nt < 8; ++nt) acc[nt] = (float4v){0.f, 0.f, 0.f, 0.f};

    char* ptw = (char*)&sU[w][0];
    const int swz = (c & 7) << 4;

    int cur = 0;
    for (int jt = jt0; jt < jtEnd; ++jt, cur ^= 1) {
        {   // prefetch next embJ + sq (drained by end-of-tile barrier)
            int jn = (jt + 1 < jtEnd) ? jt + 1 : jt;
            int nxt = cur ^ 1;
            const int4* srcJ = embqI4 + (size_t)(b * 128 + jn * 4) * 2 * 64;
            GLD16(srcJ + t, &sEmbJ[nxt][t]);
            GLD16(srcJ + t + 256, &sEmbJ[nxt][t + 256]);
            if (t < 64) GLD4(sqB + jn * 64 + t, &sSqJ[nxt][t]);
        }

        // ---- QK (swapped) + d2 only; no exp yet ----
        float d2v[4][4];
        float d2minJ[4];
#pragma unroll
        for (int J = 0; J < 4; ++J) {
            short8v a0 = *reinterpret_cast<const short8v*>(&sEmbJ[cur][(J * 2 + 0) * 64 + l]);
            short8v a1 = *reinterpret_cast<const short8v*>(&sEmbJ[cur][(J * 2 + 1) * 64 + l]);
            float4v sfr = (float4v){0.f, 0.f, 0.f, 0.f};
            sfr = __builtin_amdgcn_mfma_f32_16x16x32_bf16(a0, qkB[0], sfr, 0, 0, 0);
            sfr = __builtin_amdgcn_mfma_f32_16x16x32_bf16(a1, qkB[1], sfr, 0, 0, 0);
            float4 sqj = *reinterpret_cast<const float4*>(&sSqJ[cur][J * 16 + 4 * g]);
            d2v[J][0] = fmaxf(fmaf(-2.0f, sfr[0], sqi + sqj.x), 0.0f);
            d2v[J][1] = fmaxf(fmaf(-2.0f, sfr[1], sqi + sqj.y), 0.0f);
            d2v[J][2] = fmaxf(fmaf(-2.0f, sfr[2], sqi + sqj.z), 0.0f);
            d2v[J][3] = fmaxf(fmaf(-2.0f, sfr[3], sqi + sqj.w), 0.0f);
            d2minJ[J] = fminf(fminf(d2v[J][0], d2v[J][1]), fminf(d2v[J][2], d2v[J][3]));
        }
        float tmin = fminf(fminf(d2minJ[0], d2minJ[1]), fminf(d2minJ[2], d2minJ[3]));

        // ---- exp/pack/PV only when some p >= 1e-6 anywhere in the wave-tile ----
        if (!__all(tmin > 13.8f)) {
#pragma unroll
            for (int J = 0; J < 4; ++J) {
                unsigned long long pword = 0ull;
                if (!__all(d2minJ[J] > 13.8f)) {
                    float p0 = __expf(-d2v[J][0]);
                    float p1 = __expf(-d2v[J][1]);
                    float p2 = __expf(-d2v[J][2]);
                    float p3 = __expf(-d2v[J][3]);
                    dsum += (p0 + p1) + (p2 + p3);
                    pword = (unsigned long long)pack2bf(p0, p1) |
                            ((unsigned long long)pack2bf(p2, p3) << 32);
                }
                *reinterpret_cast<unsigned long long*>(
                    ptw + ((c * 128 + g * 8) ^ swz ^ (J * 32))) = pword;
            }
            short8v pa0 = *reinterpret_cast<const short8v*>(ptw + ((c * 128 + 0 * 64 + g * 16) ^ swz));
            short8v pa1 = *reinterpret_cast<const short8v*>(ptw + ((c * 128 + 1 * 64 + g * 16) ^ swz));
#pragma unroll
            for (int nt = 0; nt < 8; ++nt) {
                short8v z0 = zq8[(size_t)((b * 64 + jt * 2 + 0) * 8 + nt) * 64 + l];
                short8v z1 = zq8[(size_t)((b * 64 + jt * 2 + 1) * 8 + nt) * 64 + l];
                acc[nt] = __builtin_amdgcn_mfma_f32_16x16x32_bf16(pa0, z0, acc[nt], 0, 0, 0);
                acc[nt] = __builtin_amdgcn_mfma_f32_16x16x32_bf16(pa1, z1, acc[nt], 0, 0, 0);
            }
        }

        __syncthreads();  // single sync: guards sEmbJ dbuf reuse + drains prefetch
    }

    // dsum reduce over g-groups -> all lanes hold row-c sum
    dsum += __shfl_xor(dsum, 16);
    dsum += __shfl_xor(dsum, 32);

    if (njs == 1) {
        float invr[4];
#pragma unroll
        for (int r = 0; r < 4; ++r) invr[r] = 1.0f / __shfl(dsum, 4 * g + r);
#pragma unroll
        for (int r = 0; r < 4; ++r) {
            size_t row = (size_t)(b * NN + ib + w * 16 + 4 * g + r);
#pragma unroll
            for (int nt = 0; nt < 8; ++nt)
                outnum[row * DD + nt * 16 + c] = acc[nt][r] * invr[r];
        }
    } else {
        if (l < 16) den[(size_t)js * BN + b * NN + ib + w * 16 + l] = dsum;
        // skip num writes when this wave's whole j-slice carries no mass
        if (!__all(dsum < 1e-6f)) {
#pragma unroll
            for (int r = 0; r < 4; ++r) {
                size_t row = (size_t)js * BN + b * NN + ib + w * 16 + 4 * g + r;
#pragma unroll
                for (int nt = 0; nt < 8; ++nt)
                    outnum[row * DD + nt * 16 + c] = acc[nt][r];
            }
        }
    }
}

// ---------------- reduce: out = sum_js num / sum_js den, num reads gated by den ----------------
__global__ __launch_bounds__(256) void reduce_kernel(const float4* __restrict__ num,
                                                     const float* __restrict__ den,
                                                     float4* __restrict__ out,
                                                     int njs) {
    int i4 = blockIdx.x * 256 + threadIdx.x;
    int row = i4 >> 5;
    float4 ns = make_float4(0.f, 0.f, 0.f, 0.f);
    float ds = 0.f;
    for (int js = 0; js < njs; ++js) {
        float dj = den[(size_t)js * BN + row];
        ds += dj;
        if (dj >= 1e-6f) {  // slices below tau were never written (and contribute < 1e-5)
            float4 v = num[(size_t)js * ((size_t)BN * (DD / 4)) + i4];
            ns.x += v.x; ns.y += v.y; ns.z += v.z; ns.w += v.w;
        }
    }
    float inv = 1.0f / ds;
    out[i4] = make_float4(ns.x * inv, ns.y * inv, ns.z * inv, ns.w * inv);
}

extern "C" void kernel_launch(void* const* d_in, const int* in_sizes, int n_in,
                              void* d_out, int out_size, void* d_ws, size_t ws_size,
                              hipStream_t stream) {
    (void)in_sizes; (void)n_in; (void)out_size;
    const float* emb = (const float*)d_in[0];
    const float* z = (const float*)d_in[1];
    float* out = (float*)d_out;
    float* ws = (float*)d_ws;

    // ws layout (floats): sq[BN] | den[njs*BN] | num[njs*BN*DD] | embq(1M shorts) | zq(2M shorts)
    int njs = 1;
    if (ws_size >= 40ull * 1024 * 1024) njs = 4;
    else if (ws_size >= 24ull * 1024 * 1024) njs = 2;

    float* sqw = ws;
    float* denw = ws + BN;
    float* numw = denw + (size_t)njs * BN;
    size_t numFloats = (njs > 1) ? (size_t)njs * BN * DD : 0;
    short* embqw = (short*)(numw + numFloats);
    short* zqw = embqw + (size_t)BB * NN * EE;

    prep_kernel<<<1024, 256, 0, stream>>>(emb, z, embqw, zqw, sqw);

    attn_mfma<<<8 * 32 * njs, 256, 0, stream>>>(embqw, zqw, sqw,
                                                njs == 1 ? out : numw, denw, njs);

    if (njs > 1) {
        reduce_kernel<<<(BN * (DD / 4)) / 256, 256, 0, stream>>>(
            (const float4*)numw, denw, (float4*)out, njs);
    }
}